// Round 9
// baseline (619.706 us; speedup 1.0000x reference)
//
#include <hip/hip_runtime.h>
#include <hip/hip_bf16.h>

#define BB 8
#define CIN 256
#define COUT 128
#define HIN 128
#define WIN 128
#define HOUT 256
#define WOUT 256

#define CREP 6
#define UREP 6

typedef __attribute__((ext_vector_type(8))) short bf16x8;
typedef __attribute__((ext_vector_type(4))) float f32x4;

__device__ __forceinline__ short f2bf(float f) {
  __hip_bfloat16 h = __float2bfloat16(f);  // RNE
  return *reinterpret_cast<short*>(&h);
}
__device__ __forceinline__ float bf2f(short s) {
  unsigned int u = ((unsigned int)(unsigned short)s) << 16;
  return __uint_as_float(u);
}

// ---------------- Kernel 0: W fp32 -> bf16 (row-major [COUT][CIN]) --------
__global__ __launch_bounds__(256) void wconv_kernel(const float* __restrict__ wgt,
                                                    short* __restrict__ wbf) {
  int idx = (blockIdx.x * 256 + threadIdx.x) * 4;
  float4 f = *reinterpret_cast<const float4*>(wgt + idx);
  short4 pk = make_short4(f2bf(f.x), f2bf(f.y), f2bf(f.z), f2bf(f.w));
  *reinterpret_cast<short4*>(wbf + idx) = pk;
}

// ---------------- Kernel 1: conv (R7 structure) x CREP diagnostic loop ----
// DIAGNOSTIC ROUND: body repeated CREP times (identical output each rep,
// idempotent). Opaque pointer copies per rep stop cross-rep load CSE.
__global__ __launch_bounds__(256, 2) void conv1x1_kernel(const float* __restrict__ x,
                                                         const short* __restrict__ wbf,
                                                         short* __restrict__ zbf) {
  __shared__ __align__(16) short smem[128 * 128];  // 32KB
  const int h = blockIdx.x, b = blockIdx.y;
  const int t = threadIdx.x;

  const int lane = t & 63, wid = t >> 6;
  const int wm = wid >> 1, wn = wid & 1;
  const int r = lane & 15, g = lane >> 4;

  const float* xb = x + (size_t)b * (CIN * HIN * WIN) + (size_t)h * WIN;
  const int w0 = t & 127;
  const int ch = t >> 7;

#pragma unroll 1
  for (int rep = 0; rep < CREP; ++rep) {
    const float* xr = xb;
    const short* wr = wbf;
    asm volatile("" : "+v"(xr), "+v"(wr));  // block cross-rep CSE

    f32x4 acc[4][4];
#pragma unroll
    for (int i = 0; i < 4; ++i)
#pragma unroll
      for (int j = 0; j < 4; ++j)
        acc[i][j] = (f32x4){0.f, 0.f, 0.f, 0.f};

    float f0[64], f1[64];

    // issue phase-0 loads
#pragma unroll
    for (int cc = 0; cc < 8; ++cc)
#pragma unroll
      for (int i = 0; i < 8; ++i)
        f0[cc * 8 + i] = xr[(size_t)((ch * 8 + cc) * 8 + i) * (HIN * WIN) + w0];

    // cvt + LDS write phase 0
#pragma unroll
    for (int cc = 0; cc < 8; ++cc) {
      int kl = ch * 8 + cc;
      bf16x8 pk;
#pragma unroll
      for (int i = 0; i < 8; ++i) pk[i] = f2bf(f0[cc * 8 + i]);
      *reinterpret_cast<bf16x8*>(&smem[w0 * 128 + ((kl ^ (w0 & 15)) * 8)]) = pk;
    }
    __syncthreads();

    // issue phase-1 loads (overlap with MFMA phase 0)
#pragma unroll
    for (int cc = 0; cc < 8; ++cc)
#pragma unroll
      for (int i = 0; i < 8; ++i)
        f1[cc * 8 + i] = xr[(size_t)(128 + (ch * 8 + cc) * 8 + i) * (HIN * WIN) + w0];

    // MFMA phase 0
#pragma unroll
    for (int ks = 0; ks < 4; ++ks) {
      int kk = ks * 4 + g;
      bf16x8 xfr[4], wfr[4];
#pragma unroll
      for (int mt = 0; mt < 4; ++mt) {
        int p = wm * 64 + mt * 16 + r;
        xfr[mt] = *reinterpret_cast<const bf16x8*>(&smem[p * 128 + ((kk ^ (p & 15)) * 8)]);
      }
#pragma unroll
      for (int nt = 0; nt < 4; ++nt) {
        int o = wn * 64 + nt * 16 + r;
        wfr[nt] = *reinterpret_cast<const bf16x8*>(wr + (size_t)o * CIN + kk * 8);
      }
#pragma unroll
      for (int mt = 0; mt < 4; ++mt)
#pragma unroll
        for (int nt = 0; nt < 4; ++nt)
          acc[mt][nt] = __builtin_amdgcn_mfma_f32_16x16x32_bf16(xfr[mt], wfr[nt], acc[mt][nt], 0, 0, 0);
    }
    __syncthreads();

    // cvt + LDS write phase 1
#pragma unroll
    for (int cc = 0; cc < 8; ++cc) {
      int kl = ch * 8 + cc;
      bf16x8 pk;
#pragma unroll
      for (int i = 0; i < 8; ++i) pk[i] = f2bf(f1[cc * 8 + i]);
      *reinterpret_cast<bf16x8*>(&smem[w0 * 128 + ((kl ^ (w0 & 15)) * 8)]) = pk;
    }
    __syncthreads();

    // MFMA phase 1
#pragma unroll
    for (int ks = 0; ks < 4; ++ks) {
      int kk = ks * 4 + g;
      int kg = 16 + kk;
      bf16x8 xfr[4], wfr[4];
#pragma unroll
      for (int mt = 0; mt < 4; ++mt) {
        int p = wm * 64 + mt * 16 + r;
        xfr[mt] = *reinterpret_cast<const bf16x8*>(&smem[p * 128 + ((kk ^ (p & 15)) * 8)]);
      }
#pragma unroll
      for (int nt = 0; nt < 4; ++nt) {
        int o = wn * 64 + nt * 16 + r;
        wfr[nt] = *reinterpret_cast<const bf16x8*>(wr + (size_t)o * CIN + kg * 8);
      }
#pragma unroll
      for (int mt = 0; mt < 4; ++mt)
#pragma unroll
        for (int nt = 0; nt < 4; ++nt)
          acc[mt][nt] = __builtin_amdgcn_mfma_f32_16x16x32_bf16(xfr[mt], wfr[nt], acc[mt][nt], 0, 0, 0);
    }
    __syncthreads();

    // epilogue: acc -> zs[o][w] bf16 in LDS, then 256B-contiguous stores
#pragma unroll
    for (int mt = 0; mt < 4; ++mt) {
#pragma unroll
      for (int nt = 0; nt < 4; ++nt) {
        int o = wn * 64 + nt * 16 + r;
        int w4 = wm * 64 + mt * 16 + g * 4;
        int cw = w4 >> 3, sub = w4 & 7;
        short4 pk = make_short4(f2bf(acc[mt][nt][0]), f2bf(acc[mt][nt][1]),
                                f2bf(acc[mt][nt][2]), f2bf(acc[mt][nt][3]));
        *reinterpret_cast<short4*>(&smem[o * 128 + ((cw ^ (o & 15)) << 3) + sub]) = pk;
      }
    }
    __syncthreads();

    short* zb = zbf + (size_t)b * (COUT * HIN * WIN) + (size_t)h * WIN;
    const int ck = t & 15;
#pragma unroll
    for (int p = 0; p < 8; ++p) {
      int ro = p * 16 + (t >> 4);
      bf16x8 v = *reinterpret_cast<const bf16x8*>(&smem[ro * 128 + ((ck ^ (ro & 15)) << 3)]);
      *reinterpret_cast<bf16x8*>(zb + (size_t)ro * (HIN * WIN) + ck * 8) = v;
    }
    __syncthreads();  // before next rep's staging writes
  }
}

// ---------------- Kernel 2: upsample (R7 structure) x UREP diagnostic -----
#define ACF (-0.75f)
#define NEG 0.01f

__device__ __forceinline__ float cub_le1(float s) {
  return ((ACF + 2.0f) * s - (ACF + 3.0f)) * s * s + 1.0f;
}
__device__ __forceinline__ float cub_gt1(float s) {
  return (((s - 5.0f) * s + 8.0f) * s - 4.0f) * ACF;
}
__device__ __forceinline__ float4 mkw(float tt) {
  return make_float4(cub_gt1(1.0f + tt), cub_le1(tt), cub_le1(1.0f - tt), cub_gt1(2.0f - tt));
}

__global__ __launch_bounds__(256) void upsample_kernel(const short* __restrict__ zbf,
                                                       const float* __restrict__ bias,
                                                       float* __restrict__ out) {
  __shared__ float zrow[20][128];
  __shared__ float trow[20][256];

  const int bx = blockIdx.x;
  const int itile = bx & 7;
  const int o = bx >> 3;
  const int b = blockIdx.y;
  const int t = threadIdx.x;

  const int m0 = itile * 16;
  const int hmin = max(m0 - 2, 0);
  const int hmax = min(m0 + 15 + 2, HIN - 1);
  const int nh = hmax - hmin + 1;  // <= 20

  const float bv = bias[o];

#pragma unroll 1
  for (int rep = 0; rep < UREP; ++rep) {
    const short* zr0 = zbf;
    asm volatile("" : "+v"(zr0));  // block cross-rep CSE

    {
      const short* zb = zr0 + ((size_t)b * COUT + o) * (HIN * WIN);
      for (int q = t; q < nh * 16; q += 256) {
        int hr = q >> 4, c8 = (q & 15) * 8;
        bf16x8 v = *reinterpret_cast<const bf16x8*>(zb + (size_t)(hmin + hr) * WIN + c8);
        float4 lo = make_float4(bf2f(v[0]), bf2f(v[1]), bf2f(v[2]), bf2f(v[3]));
        float4 hi = make_float4(bf2f(v[4]), bf2f(v[5]), bf2f(v[6]), bf2f(v[7]));
        *reinterpret_cast<float4*>(&zrow[hr][c8]) = lo;
        *reinterpret_cast<float4*>(&zrow[hr][c8 + 4]) = hi;
      }
    }
    __syncthreads();

    {
      const int u = t & 127;
      const int pr = t >> 7;
      const float uf = (float)u;
      const float4 wA = mkw((255.0f - uf) * (1.0f / 255.0f));
      const float4 wB = mkw((127.0f - uf) * (1.0f / 255.0f));
      const int i0c = max(u - 2, 0);
      const int i1c = max(u - 1, 0);
      const int i2c = u;
      const int i3c = min(u + 1, WIN - 1);
      const int i4c = min(u + 2, WIN - 1);
      for (int hr = pr; hr < nh; hr += 2) {
        float z0 = zrow[hr][i0c], z1 = zrow[hr][i1c], z2 = zrow[hr][i2c];
        float z3 = zrow[hr][i3c], z4 = zrow[hr][i4c];
        float oa = wA.x * z0 + wA.y * z1 + wA.z * z2 + wA.w * z3;
        float ob = wB.x * z1 + wB.y * z2 + wB.z * z3 + wB.w * z4;
        *reinterpret_cast<float2*>(&trow[hr][u * 2]) = make_float2(oa, ob);
      }
    }
    __syncthreads();

    const int j4 = t & 63;
    const int iw = t >> 6;
    float* obase = out + ((size_t)b * COUT + o) * (HOUT * WOUT);
    for (int mm = iw; mm < 16; mm += 4) {
      int m = m0 + mm;
      float mf = (float)m;
      float4 wA = mkw((255.0f - mf) * (1.0f / 255.0f));
      float4 wB = mkw((127.0f - mf) * (1.0f / 255.0f));
      int r0 = max(m - 2, 0) - hmin;
      int r1 = max(m - 1, 0) - hmin;
      int r2 = m - hmin;
      int r3 = min(m + 1, HIN - 1) - hmin;
      int r4 = min(m + 2, HIN - 1) - hmin;
      float4 t0 = *reinterpret_cast<const float4*>(&trow[r0][j4 * 4]);
      float4 t1 = *reinterpret_cast<const float4*>(&trow[r1][j4 * 4]);
      float4 t2 = *reinterpret_cast<const float4*>(&trow[r2][j4 * 4]);
      float4 t3 = *reinterpret_cast<const float4*>(&trow[r3][j4 * 4]);
      float4 t4 = *reinterpret_cast<const float4*>(&trow[r4][j4 * 4]);
      f32x4 rA, rB;
      rA.x = wA.x * t0.x + wA.y * t1.x + wA.z * t2.x + wA.w * t3.x + bv;
      rA.y = wA.x * t0.y + wA.y * t1.y + wA.z * t2.y + wA.w * t3.y + bv;
      rA.z = wA.x * t0.z + wA.y * t1.z + wA.z * t2.z + wA.w * t3.z + bv;
      rA.w = wA.x * t0.w + wA.y * t1.w + wA.z * t2.w + wA.w * t3.w + bv;
      rB.x = wB.x * t1.x + wB.y * t2.x + wB.z * t3.x + wB.w * t4.x + bv;
      rB.y = wB.x * t1.y + wB.y * t2.y + wB.z * t3.y + wB.w * t4.y + bv;
      rB.z = wB.x * t1.z + wB.y * t2.z + wB.z * t3.z + wB.w * t4.z + bv;
      rB.w = wB.x * t1.w + wB.y * t2.w + wB.z * t3.w + wB.w * t4.w + bv;
      rA.x = rA.x >= 0.f ? rA.x : rA.x * NEG;
      rA.y = rA.y >= 0.f ? rA.y : rA.y * NEG;
      rA.z = rA.z >= 0.f ? rA.z : rA.z * NEG;
      rA.w = rA.w >= 0.f ? rA.w : rA.w * NEG;
      rB.x = rB.x >= 0.f ? rB.x : rB.x * NEG;
      rB.y = rB.y >= 0.f ? rB.y : rB.y * NEG;
      rB.z = rB.z >= 0.f ? rB.z : rB.z * NEG;
      rB.w = rB.w >= 0.f ? rB.w : rB.w * NEG;
      int iA = itile * 32 + 2 * mm;
      __builtin_nontemporal_store(rA, reinterpret_cast<f32x4*>(obase + (size_t)iA * WOUT + j4 * 4));
      __builtin_nontemporal_store(rB, reinterpret_cast<f32x4*>(obase + (size_t)(iA + 1) * WOUT + j4 * 4));
    }
    __syncthreads();  // before next rep's zrow writes
  }
}

extern "C" void kernel_launch(void* const* d_in, const int* in_sizes, int n_in,
                              void* d_out, int out_size, void* d_ws, size_t ws_size,
                              hipStream_t stream) {
  const float* x = (const float*)d_in[0];
  const float* wgt = (const float*)d_in[1];
  const float* bias = (const float*)d_in[2];
  float* out = (float*)d_out;

  short* zbf = (short*)d_ws;
  short* wbf = (short*)((char*)d_ws + (size_t)BB * COUT * HIN * WIN * sizeof(short));

  wconv_kernel<<<dim3(COUT * CIN / (256 * 4)), 256, 0, stream>>>(wgt, wbf);
  conv1x1_kernel<<<dim3(HIN, BB), 256, 0, stream>>>(x, wbf, zbf);
  upsample_kernel<<<dim3(COUT * 8, BB), 256, 0, stream>>>(zbf, bias, out);
}

// Round 10
// 88.411 us; speedup vs baseline: 7.0094x; 7.0094x over previous
//
#include <hip/hip_runtime.h>
#include <hip/hip_bf16.h>

#define BB 8
#define CIN 256
#define COUT 128
#define HIN 128
#define WIN 128
#define HOUT 256
#define WOUT 256

typedef __attribute__((ext_vector_type(8))) short bf16x8;
typedef __attribute__((ext_vector_type(4))) float f32x4;

__device__ __forceinline__ short f2bf(float f) {
  __hip_bfloat16 h = __float2bfloat16(f);  // RNE
  return *reinterpret_cast<short*>(&h);
}
__device__ __forceinline__ float bf2f(short s) {
  unsigned int u = ((unsigned int)(unsigned short)s) << 16;
  return __uint_as_float(u);
}

typedef __attribute__((address_space(3))) unsigned int lds_u32;
typedef const __attribute__((address_space(1))) unsigned int glb_u32;
__device__ __forceinline__ void gload16(const float* g, float* l) {
  // async global->LDS, 16B/lane: dest = wave-uniform base + lane*16
  __builtin_amdgcn_global_load_lds((glb_u32*)g, (lds_u32*)l, 16, 0, 0);
}

// ---------------- Kernel 0: W fp32 -> bf16 (row-major [COUT][CIN]) --------
__global__ __launch_bounds__(256) void wconv_kernel(const float* __restrict__ wgt,
                                                    short* __restrict__ wbf) {
  int idx = (blockIdx.x * 256 + threadIdx.x) * 4;
  float4 f = *reinterpret_cast<const float4*>(wgt + idx);
  short4 pk = make_short4(f2bf(f.x), f2bf(f.y), f2bf(f.z), f2bf(f.w));
  *reinterpret_cast<short4*>(wbf + idx) = pk;
}

// ---------------- Kernel 1: z[b][o][h][w] = sum_c W[o][c] x[b][c][h][w] ----
// grid (128 h, 8 b), 256 threads (4 waves, 2x2 wave tile over 128w x 128o).
// Staging via global_load_lds width=16: x staged as F32 [64c][128w] per phase
// (32KB), zero VGPR cost, 8 in-flight 1KB instructions per wave. bf16 cvt
// happens at fragment-read time (identical math to pre-cvt). 4 phases of 64c.
// Epilogue reuses the same 32KB LDS for the z transpose -> 256B z stores.
__global__ __launch_bounds__(256, 4) void conv1x1_kernel(const float* __restrict__ x,
                                                         const short* __restrict__ wbf,
                                                         short* __restrict__ zbf) {
  __shared__ __align__(16) float smemf[64 * 128];  // 32KB staging + epilogue
  short* smems = (short*)smemf;
  const int h = blockIdx.x, b = blockIdx.y;
  const int t = threadIdx.x;
  const int lane = t & 63, wid = t >> 6;
  const int wm = wid >> 1, wn = wid & 1;
  const int r = lane & 15, g = lane >> 4;

  const float* xb = x + (size_t)b * (CIN * HIN * WIN) + (size_t)h * WIN;

  f32x4 acc[4][4];
#pragma unroll
  for (int i = 0; i < 4; ++i)
#pragma unroll
    for (int j = 0; j < 4; ++j)
      acc[i][j] = (f32x4){0.f, 0.f, 0.f, 0.f};

  const int lplane = lane >> 5;     // which of 2 planes this lane's 16B lands in
  const int lw4 = (lane & 31) * 4;  // float offset within plane

  for (int ph = 0; ph < 4; ++ph) {
    // ---- stage 64 c-planes (f32): wave wid covers planes [wid*16, +16) ----
    const int cbase = ph * 64 + wid * 16;
#pragma unroll
    for (int i = 0; i < 8; ++i) {
      const float* src = xb + (size_t)(cbase + i * 2 + lplane) * (HIN * WIN) + lw4;
      float* dst = &smemf[(wid * 16 + i * 2) * 128];
      gload16(src, dst);
    }
    asm volatile("s_waitcnt vmcnt(0)" ::: "memory");
    __syncthreads();

    // ---- 2 K-steps over this phase's 64 channels ----
#pragma unroll
    for (int ks = 0; ks < 2; ++ks) {
      const int cl0 = ks * 32 + g * 8;       // local c for this lane's fragment
      const int kg = ph * 8 + ks * 4 + g;    // global 8-c chunk (for W)
      bf16x8 xfr[4], wfr[4];
#pragma unroll
      for (int mt = 0; mt < 4; ++mt) {
        const int w = wm * 64 + mt * 16 + r;
#pragma unroll
        for (int j = 0; j < 8; ++j)
          xfr[mt][j] = f2bf(smemf[(cl0 + j) * 128 + w]);
      }
#pragma unroll
      for (int nt = 0; nt < 4; ++nt) {
        const int o = wn * 64 + nt * 16 + r;
        wfr[nt] = *reinterpret_cast<const bf16x8*>(wbf + (size_t)o * CIN + kg * 8);
      }
#pragma unroll
      for (int mt = 0; mt < 4; ++mt)
#pragma unroll
        for (int nt = 0; nt < 4; ++nt)
          acc[mt][nt] = __builtin_amdgcn_mfma_f32_16x16x32_bf16(xfr[mt], wfr[nt], acc[mt][nt], 0, 0, 0);
    }
    __syncthreads();  // compute done before next phase overwrites LDS
  }

  // ---- epilogue: acc -> zs[o][w] bf16 in LDS (16B-chunk XOR swizzle),
  //      then coalesced 256B-contiguous stores per o-row ----
#pragma unroll
  for (int mt = 0; mt < 4; ++mt) {
#pragma unroll
    for (int nt = 0; nt < 4; ++nt) {
      int o = wn * 64 + nt * 16 + r;
      int w4 = wm * 64 + mt * 16 + g * 4;
      int cw = w4 >> 3, sub = w4 & 7;
      short4 pk = make_short4(f2bf(acc[mt][nt][0]), f2bf(acc[mt][nt][1]),
                              f2bf(acc[mt][nt][2]), f2bf(acc[mt][nt][3]));
      *reinterpret_cast<short4*>(&smems[o * 128 + ((cw ^ (o & 15)) << 3) + sub]) = pk;
    }
  }
  __syncthreads();

  short* zb = zbf + (size_t)b * (COUT * HIN * WIN) + (size_t)h * WIN;
  const int ck = t & 15;
#pragma unroll
  for (int p = 0; p < 8; ++p) {
    int ro = p * 16 + (t >> 4);
    bf16x8 v = *reinterpret_cast<const bf16x8*>(&smems[ro * 128 + ((ck ^ (ro & 15)) << 3)]);
    *reinterpret_cast<bf16x8*>(zb + (size_t)ro * (HIN * WIN) + ck * 8) = v;
  }
}

// ---------------- Kernel 2: separable bicubic 2x + bias + LeakyReLU -------
#define ACF (-0.75f)
#define NEG 0.01f

__device__ __forceinline__ float cub_le1(float s) {
  return ((ACF + 2.0f) * s - (ACF + 3.0f)) * s * s + 1.0f;
}
__device__ __forceinline__ float cub_gt1(float s) {
  return (((s - 5.0f) * s + 8.0f) * s - 4.0f) * ACF;
}
__device__ __forceinline__ float4 mkw(float tt) {
  return make_float4(cub_gt1(1.0f + tt), cub_le1(tt), cub_le1(1.0f - tt), cub_gt1(2.0f - tt));
}

__global__ __launch_bounds__(256) void upsample_kernel(const short* __restrict__ zbf,
                                                       const float* __restrict__ bias,
                                                       float* __restrict__ out) {
  __shared__ float zrow[20][128];
  __shared__ float trow[20][256];

  const int bx = blockIdx.x;
  const int itile = bx & 7;
  const int o = bx >> 3;
  const int b = blockIdx.y;
  const int t = threadIdx.x;

  const int m0 = itile * 16;
  const int hmin = max(m0 - 2, 0);
  const int hmax = min(m0 + 15 + 2, HIN - 1);
  const int nh = hmax - hmin + 1;  // <= 20

  {
    const short* zb = zbf + ((size_t)b * COUT + o) * (HIN * WIN);
    for (int q = t; q < nh * 16; q += 256) {
      int hr = q >> 4, c8 = (q & 15) * 8;
      bf16x8 v = *reinterpret_cast<const bf16x8*>(zb + (size_t)(hmin + hr) * WIN + c8);
      float4 lo = make_float4(bf2f(v[0]), bf2f(v[1]), bf2f(v[2]), bf2f(v[3]));
      float4 hi = make_float4(bf2f(v[4]), bf2f(v[5]), bf2f(v[6]), bf2f(v[7]));
      *reinterpret_cast<float4*>(&zrow[hr][c8]) = lo;
      *reinterpret_cast<float4*>(&zrow[hr][c8 + 4]) = hi;
    }
  }
  __syncthreads();

  {
    const int u = t & 127;
    const int pr = t >> 7;
    const float uf = (float)u;
    const float4 wA = mkw((255.0f - uf) * (1.0f / 255.0f));
    const float4 wB = mkw((127.0f - uf) * (1.0f / 255.0f));
    const int i0c = max(u - 2, 0);
    const int i1c = max(u - 1, 0);
    const int i2c = u;
    const int i3c = min(u + 1, WIN - 1);
    const int i4c = min(u + 2, WIN - 1);
    for (int hr = pr; hr < nh; hr += 2) {
      float z0 = zrow[hr][i0c], z1 = zrow[hr][i1c], z2 = zrow[hr][i2c];
      float z3 = zrow[hr][i3c], z4 = zrow[hr][i4c];
      float oa = wA.x * z0 + wA.y * z1 + wA.z * z2 + wA.w * z3;
      float ob = wB.x * z1 + wB.y * z2 + wB.z * z3 + wB.w * z4;
      *reinterpret_cast<float2*>(&trow[hr][u * 2]) = make_float2(oa, ob);
    }
  }
  __syncthreads();

  const float bv = bias[o];
  const int j4 = t & 63;
  const int iw = t >> 6;
  float* obase = out + ((size_t)b * COUT + o) * (HOUT * WOUT);
  for (int mm = iw; mm < 16; mm += 4) {
    int m = m0 + mm;
    float mf = (float)m;
    float4 wA = mkw((255.0f - mf) * (1.0f / 255.0f));
    float4 wB = mkw((127.0f - mf) * (1.0f / 255.0f));
    int r0 = max(m - 2, 0) - hmin;
    int r1 = max(m - 1, 0) - hmin;
    int r2 = m - hmin;
    int r3 = min(m + 1, HIN - 1) - hmin;
    int r4 = min(m + 2, HIN - 1) - hmin;
    float4 t0 = *reinterpret_cast<const float4*>(&trow[r0][j4 * 4]);
    float4 t1 = *reinterpret_cast<const float4*>(&trow[r1][j4 * 4]);
    float4 t2 = *reinterpret_cast<const float4*>(&trow[r2][j4 * 4]);
    float4 t3 = *reinterpret_cast<const float4*>(&trow[r3][j4 * 4]);
    float4 t4 = *reinterpret_cast<const float4*>(&trow[r4][j4 * 4]);
    f32x4 rA, rB;
    rA.x = wA.x * t0.x + wA.y * t1.x + wA.z * t2.x + wA.w * t3.x + bv;
    rA.y = wA.x * t0.y + wA.y * t1.y + wA.z * t2.y + wA.w * t3.y + bv;
    rA.z = wA.x * t0.z + wA.y * t1.z + wA.z * t2.z + wA.w * t3.z + bv;
    rA.w = wA.x * t0.w + wA.y * t1.w + wA.z * t2.w + wA.w * t3.w + bv;
    rB.x = wB.x * t1.x + wB.y * t2.x + wB.z * t3.x + wB.w * t4.x + bv;
    rB.y = wB.x * t1.y + wB.y * t2.y + wB.z * t3.y + wB.w * t4.y + bv;
    rB.z = wB.x * t1.z + wB.y * t2.z + wB.z * t3.z + wB.w * t4.z + bv;
    rB.w = wB.x * t1.w + wB.y * t2.w + wB.z * t3.w + wB.w * t4.w + bv;
    rA.x = rA.x >= 0.f ? rA.x : rA.x * NEG;
    rA.y = rA.y >= 0.f ? rA.y : rA.y * NEG;
    rA.z = rA.z >= 0.f ? rA.z : rA.z * NEG;
    rA.w = rA.w >= 0.f ? rA.w : rA.w * NEG;
    rB.x = rB.x >= 0.f ? rB.x : rB.x * NEG;
    rB.y = rB.y >= 0.f ? rB.y : rB.y * NEG;
    rB.z = rB.z >= 0.f ? rB.z : rB.z * NEG;
    rB.w = rB.w >= 0.f ? rB.w : rB.w * NEG;
    int iA = itile * 32 + 2 * mm;
    __builtin_nontemporal_store(rA, reinterpret_cast<f32x4*>(obase + (size_t)iA * WOUT + j4 * 4));
    __builtin_nontemporal_store(rB, reinterpret_cast<f32x4*>(obase + (size_t)(iA + 1) * WOUT + j4 * 4));
  }
}

extern "C" void kernel_launch(void* const* d_in, const int* in_sizes, int n_in,
                              void* d_out, int out_size, void* d_ws, size_t ws_size,
                              hipStream_t stream) {
  const float* x = (const float*)d_in[0];
  const float* wgt = (const float*)d_in[1];
  const float* bias = (const float*)d_in[2];
  float* out = (float*)d_out;

  short* zbf = (short*)d_ws;
  short* wbf = (short*)((char*)d_ws + (size_t)BB * COUT * HIN * WIN * sizeof(short));

  wconv_kernel<<<dim3(COUT * CIN / (256 * 4)), 256, 0, stream>>>(wgt, wbf);
  conv1x1_kernel<<<dim3(HIN, BB), 256, 0, stream>>>(x, wbf, zbf);
  upsample_kernel<<<dim3(COUT * 8, BB), 256, 0, stream>>>(zbf, bias, out);
}